// Round 1
// baseline (490.239 us; speedup 1.0000x reference)
//
#include <hip/hip_runtime.h>
#include <hip/hip_fp16.h>
#include <hip/hip_cooperative_groups.h>

namespace cg = cooperative_groups;

// B=256 queries, D=2048, d=64 hash dim, N=100000 database, C=100 classes,
// K=1000 SMALLEST-sim selection. Inputs f32, labels int, output f32.
//
// R7: ONE cooperative kernel (512 blocks x 256 thr, 2 blocks/CU co-resident),
// 5 grid.sync()s replace 8 dispatch boundaries (~10 us each in this harness).
// Phases: P0a zero(scal,belowCnt) | P0b cvtnorm+out+detect | P1 mhist |
// P2 scan | P3 mclass | P4 final. histg stored as u16 (counts <= cpb=1600).
//
// Math identical to R6 (MFMA f16 screen with rigorous error bound M,
// bucket histogram -> threshold bucket -> certain-below / certain-out /
// candidate window, exact f64 resolve of ~265 candidates/row).

#define NBK 256          // buckets per row histogram (pow2)
#define CAPC 1024        // per-row candidate capacity at final (expected ~265)
#define CAPB 64          // per-(chunk,row) segment capacity (expected ~4)
#define MROWS 32         // out-rows per MFMA block (two 16-row tiles)
#define NCHX 64          // code-chunks for MFMA passes
#define NCLS 100

typedef _Float16 half8 __attribute__((ext_vector_type(8)));
typedef float floatx4 __attribute__((ext_vector_type(4)));

struct Scal { int shift; unsigned cmaxsq_bits; };

struct KArgs {
  const float* x; const float* W; const float* codes; const int* labels; const int* Kp;
  double* out64; float2* rowTH; unsigned short* out16; double* B1sq;
  Scal* scal; unsigned* belowCnt; unsigned* ccnt; unsigned* cand;
  unsigned short* histg; unsigned short* codes16; float* outp;
  int N, Npad, cpb, B, D;
};

static __device__ __forceinline__ unsigned packh2(float a, float b) {
  _Float16 ha = (_Float16)a, hb = (_Float16)b;      // RNE
  unsigned short ua, ub;
  __builtin_memcpy(&ua, &ha, 2); __builtin_memcpy(&ub, &hb, 2);
  return (unsigned)ua | ((unsigned)ub << 16);
}

// shared range math (1-ulp discrepancies absorbed by 2M margins, M>=0.05)
static __device__ __forceinline__ void rowRange(double b1sq, double cmax,
                                                double& lo, double& inv, double& bw) {
  double hr = 0.5 * sqrt(b1sq * cmax) * 1.000001 + 9.0;  // +9 >> M
  lo = 50.0 - hr;
  bw = (2.0 * hr) / (double)NBK;
  inv = (double)NBK / (2.0 * hr);
}

// exact f64 dot for candidate resolution (order-stable chain)
static __device__ __forceinline__ double dot1(const float* __restrict__ codes, int n,
                                              const double* __restrict__ od) {
  const float4* crow = (const float4*)(codes + (size_t)n * 64);
  double a = 0.0;
#pragma unroll
  for (int i = 0; i < 16; ++i) {
    float4 q = crow[i];
    a = fma((double)q.x, od[i*4+0], a);
    a = fma((double)q.y, od[i*4+1], a);
    a = fma((double)q.z, od[i*4+2], a);
    a = fma((double)q.w, od[i*4+3], a);
  }
  return a;
}

// ---- MFMA A-fragment loader (mfma_f32_16x16x32_f16 layout, m89-verified):
//   A: lane holds A[m = lane&15][k = (lane>>4)*8 + j]; D: reg r = D[(lane>>4)*4+r][lane&15]
static __device__ __forceinline__ void loadA(const unsigned short* __restrict__ out16,
                                             int m0, int mr, int quad,
                                             half8& a00, half8& a01, half8& a10, half8& a11) {
  const uint4* o4 = (const uint4*)out16;
  uint4 u;
  u = o4[(size_t)(m0 + mr) * 8 + quad];          __builtin_memcpy(&a00, &u, 16);
  u = o4[(size_t)(m0 + mr) * 8 + 4 + quad];      __builtin_memcpy(&a01, &u, 16);
  u = o4[(size_t)(m0 + 16 + mr) * 8 + quad];     __builtin_memcpy(&a10, &u, 16);
  u = o4[(size_t)(m0 + 16 + mr) * 8 + 4 + quad]; __builtin_memcpy(&a11, &u, 16);
}

struct SMemP0 { double red[256]; float fred[256]; int flag; };
struct SMemP1 { unsigned hist[MROWS * NBK]; float sP[MROWS]; float sQ[MROWS]; };
struct SMemP2 { unsigned s[NBK]; };
struct SMemP3 { unsigned lab[MROWS * NCLS]; unsigned lcnt[MROWS]; float sTL[MROWS]; float sTH[MROWS]; };
struct SMemP4 { double key[CAPC]; int kidx[CAPC]; unsigned lab[NCLS]; int soff[NCHX + 1]; unsigned btot; };
union SMem { SMemP0 p0; SMemP1 p1; SMemP2 p2; SMemP3 p3; SMemP4 p4; };  // max ~32.3 KB

__global__ __launch_bounds__(256, 2) void k_fused(KArgs A) {
  __shared__ SMem sm;
  cg::grid_group grid = cg::this_grid();
  const int tid = (int)threadIdx.x;
  const int blk = (int)blockIdx.x;
  const int nblk = (int)gridDim.x;
  const int B = A.B, N = A.N, Npad = A.Npad, cpb = A.cpb, D = A.D;

  // =============== P0a: zero scal->cmaxsq + belowCnt ===============
  {
    int gtid = blk * 256 + tid;
    int tot = B * NCLS;
    if (gtid < tot) A.belowCnt[gtid] = 0u;
    if (gtid == tot) A.scal->cmaxsq_bits = 0u;
  }
  grid.sync();

  // =============== P0b: cvtnorm (blk<Npad/256) + out (blk>=256) + detect ===============
  if (blk < Npad / 256) {        // codes f32 -> f16 (RNE) + max ||code||^2
    int n = blk * 256 + tid;
    float m = 0.0f;
    if (n < N) {
      const float4* crow = (const float4*)(A.codes + (size_t)n * 64);
      uint4* orow = (uint4*)(A.codes16 + (size_t)n * 64);
      double c2 = 0.0;
#pragma unroll
      for (int i = 0; i < 8; ++i) {
        float4 qa = crow[2*i], qb = crow[2*i+1];
        c2 = fma((double)qa.x, (double)qa.x, c2); c2 = fma((double)qa.y, (double)qa.y, c2);
        c2 = fma((double)qa.z, (double)qa.z, c2); c2 = fma((double)qa.w, (double)qa.w, c2);
        c2 = fma((double)qb.x, (double)qb.x, c2); c2 = fma((double)qb.y, (double)qb.y, c2);
        c2 = fma((double)qb.z, (double)qb.z, c2); c2 = fma((double)qb.w, (double)qb.w, c2);
        uint4 o;
        o.x = packh2(qa.x, qa.y); o.y = packh2(qa.z, qa.w);
        o.z = packh2(qb.x, qb.y); o.w = packh2(qb.z, qb.w);
        orow[i] = o;
      }
      m = (float)(c2 * 1.000001);
    } else {                     // n < Npad always here
      uint4* orow = (uint4*)(A.codes16 + (size_t)n * 64);
      uint4 z = {0u, 0u, 0u, 0u};
#pragma unroll
      for (int i = 0; i < 8; ++i) orow[i] = z;
    }
    sm.p0.fred[tid] = m; __syncthreads();
    for (int off = 128; off > 0; off >>= 1) {
      if (tid < off) sm.p0.fred[tid] = fmaxf(sm.p0.fred[tid], sm.p0.fred[tid + off]);
      __syncthreads();
    }
    if (tid == 0) atomicMax(&A.scal->cmaxsq_bits, __float_as_uint(sm.p0.fred[0]));
    __syncthreads();
  }
  if (blk >= 256 && blk < 256 + B) {   // out = x @ W in f64 (+f16 copy), ||out_b||^2
    int b = blk - 256;
    int t = tid & 63, w = tid >> 6;    // w in 0..3
    int kc = D >> 2;                   // 512 for D=2048
    int k0 = w * kc;
    const float* xr = A.x + (size_t)b * D;
    double a[8];
#pragma unroll
    for (int j = 0; j < 8; ++j) a[j] = 0.0;
    for (int k = k0; k < k0 + kc; k += 8) {
      float4 xv0 = *(const float4*)(xr + k);
      float4 xv1 = *(const float4*)(xr + k + 4);
      float xs[8] = {xv0.x, xv0.y, xv0.z, xv0.w, xv1.x, xv1.y, xv1.z, xv1.w};
#pragma unroll
      for (int j = 0; j < 8; ++j)
        a[j] = fma((double)xs[j], (double)A.W[(size_t)(k + j) * 64 + t], a[j]);
    }
    __syncthreads();
    sm.p0.red[tid] = ((a[0] + a[1]) + (a[2] + a[3])) + ((a[4] + a[5]) + (a[6] + a[7]));
    __syncthreads();
    if (w == 0) {
      double o = 0.0;
#pragma unroll
      for (int j = 0; j < 4; ++j) o += sm.p0.red[t + 64 * j];
      A.out64[(size_t)b * 64 + t] = o;
      _Float16 h = (_Float16)(float)o;       // RNE
      unsigned short us; __builtin_memcpy(&us, &h, 2);
      A.out16[(size_t)b * 64 + t] = us;
      sm.p0.red[t] = o * o;                  // same-wave lanes: lockstep-safe
    }
    __syncthreads();
    if (tid == 0) {
      double s = 0.0;
      for (int i = 0; i < 64; ++i) s += sm.p0.red[i];
      A.B1sq[b] = s;
    }
  }
  if (blk == nblk - 1) {               // labels layout: int64 pairs vs int32
    if (tid == 0) sm.p0.flag = 0;
    __syncthreads();
    int m = N < 256 ? N : 256;
    if (tid < m && A.labels[2 * tid + 1] != 0) atomicOr(&sm.p0.flag, 1);
    __syncthreads();
    if (tid == 0) A.scal->shift = sm.p0.flag ? 0 : 1;  // label(n)=labels[n<<shift]
  }
  grid.sync();

  // =============== P1: MFMA screen -> per-(chunk,row) u16 histogram slab ===============
  {
    int cx = blk % NCHX, y = blk / NCHX;
    int m0 = y * MROWS;
    for (int i = tid; i < MROWS * NBK; i += 256) sm.p1.hist[i] = 0u;
    if (tid < MROWS) {
      double lo, inv, bw;
      rowRange(A.B1sq[m0 + tid], (double)__uint_as_float(A.scal->cmaxsq_bits), lo, inv, bw);
      sm.p1.sP[tid] = (float)(-0.5 * inv);   // bucket = trunc(d*P + Q), monotone in v
      sm.p1.sQ[tid] = (float)((50.0 - lo) * inv);
    }
    __syncthreads();
    int l = tid & 63, w = tid >> 6;
    int quad = l >> 4, mr = l & 15;
    half8 a00, a01, a10, a11;
    loadA(A.out16, m0, mr, quad, a00, a01, a10, a11);
    float P0[4], Q0[4], P1[4], Q1[4];
#pragma unroll
    for (int r = 0; r < 4; ++r) {
      P0[r] = sm.p1.sP[quad*4 + r];      Q0[r] = sm.p1.sQ[quad*4 + r];
      P1[r] = sm.p1.sP[16 + quad*4 + r]; Q1[r] = sm.p1.sQ[16 + quad*4 + r];
    }
    int cstart = cx * cpb;
    int cend = cstart + cpb; if (cend > N) cend = N;
    const uint4* c4 = (const uint4*)A.codes16;
    floatx4 z = {0.f, 0.f, 0.f, 0.f};
    for (int base = cstart; base < cend; base += 64) {
      int nrow = base + w * 16 + mr;
      int nc = nrow < Npad ? nrow : Npad - 1;
      uint4 ub0 = c4[(size_t)nc * 8 + quad];
      uint4 ub1 = c4[(size_t)nc * 8 + 4 + quad];
      half8 b0, b1;
      __builtin_memcpy(&b0, &ub0, 16); __builtin_memcpy(&b1, &ub1, 16);
      floatx4 d0 = __builtin_amdgcn_mfma_f32_16x16x32_f16(a00, b0, z, 0, 0, 0);
      d0 = __builtin_amdgcn_mfma_f32_16x16x32_f16(a01, b1, d0, 0, 0, 0);
      floatx4 d1 = __builtin_amdgcn_mfma_f32_16x16x32_f16(a10, b0, z, 0, 0, 0);
      d1 = __builtin_amdgcn_mfma_f32_16x16x32_f16(a11, b1, d1, 0, 0, 0);
      if (nrow < N) {
#pragma unroll
        for (int r = 0; r < 4; ++r) {
          int bk0 = (int)fmaf(d0[r], P0[r], Q0[r]);
          bk0 = bk0 < 0 ? 0 : (bk0 > NBK-1 ? NBK-1 : bk0);
          atomicAdd(&sm.p1.hist[(quad*4 + r) * NBK + bk0], 1u);   // LDS: local, fast
          int bk1 = (int)fmaf(d1[r], P1[r], Q1[r]);
          bk1 = bk1 < 0 ? 0 : (bk1 > NBK-1 ? NBK-1 : bk1);
          atomicAdd(&sm.p1.hist[(16 + quad*4 + r) * NBK + bk1], 1u);
        }
      }
    }
    __syncthreads();
    // exclusive slab, plain coalesced u16 stores (counts <= cpb=1600 < 65535)
    for (int i = tid; i < MROWS * NBK; i += 256)
      A.histg[((size_t)cx * B + (m0 + (i >> 8))) * NBK + (i & (NBK - 1))] =
          (unsigned short)sm.p1.hist[i];
  }
  grid.sync();

  // =============== P2: per-row scan -> threshold bucket -> [TL,TH] ===============
  if (blk < B) {
    int b = blk;
    unsigned acc = 0;
    for (int cx = 0; cx < NCHX; ++cx)
      acc += (unsigned)A.histg[((size_t)cx * B + b) * NBK + tid];   // coalesced u16
    sm.p2.s[tid] = acc;
    __syncthreads();
    for (int off = 1; off < NBK; off <<= 1) {
      unsigned add = (tid >= off) ? sm.p2.s[tid - off] : 0u;
      __syncthreads();
      sm.p2.s[tid] += add;
      __syncthreads();
    }
    unsigned K = (unsigned)A.Kp[0];
    unsigned cum = sm.p2.s[tid], prev = tid ? sm.p2.s[tid - 1] : 0u;
    if (cum >= K && prev < K) {          // exactly one thread: tb = tid
      double lo, inv, bw;
      double cmax = (double)__uint_as_float(A.scal->cmaxsq_bits);
      rowRange(A.B1sq[b], cmax, lo, inv, bw);
      double S = sqrt(A.B1sq[b] * cmax);
      double M = 0.5 * S * 1.1e-3 + 0.05;    // f16 cvt + f32 accum bound
      double lot = lo + (double)tid * bw;
      A.rowTH[b] = make_float2((float)(lot - 2.0 * M - 1e-3),
                               (float)(lot + bw + 2.0 * M + 1e-3));
    }
  }
  grid.sync();

  // =============== P3: MFMA recompute -> below label-hist / candidate segments ===============
  {
    int cx = blk % NCHX, y = blk / NCHX;
    int m0 = y * MROWS;
    for (int i = tid; i < MROWS * NCLS; i += 256) sm.p3.lab[i] = 0u;
    if (tid < MROWS) {
      sm.p3.lcnt[tid] = 0u;
      float2 th = A.rowTH[m0 + tid];
      sm.p3.sTL[tid] = th.x; sm.p3.sTH[tid] = th.y;
    }
    __syncthreads();
    int l = tid & 63, w = tid >> 6;
    int quad = l >> 4, mr = l & 15;
    half8 a00, a01, a10, a11;
    loadA(A.out16, m0, mr, quad, a00, a01, a10, a11);
    float TL0[4], TH0[4], TL1[4], TH1[4];
#pragma unroll
    for (int r = 0; r < 4; ++r) {
      TL0[r] = sm.p3.sTL[quad*4 + r];      TH0[r] = sm.p3.sTH[quad*4 + r];
      TL1[r] = sm.p3.sTL[16 + quad*4 + r]; TH1[r] = sm.p3.sTH[16 + quad*4 + r];
    }
    int shift = A.scal->shift;
    int cstart = cx * cpb;
    int cend = cstart + cpb; if (cend > N) cend = N;
    const uint4* c4 = (const uint4*)A.codes16;
    floatx4 z = {0.f, 0.f, 0.f, 0.f};
    for (int base = cstart; base < cend; base += 64) {
      int nrow = base + w * 16 + mr;
      int nc = nrow < Npad ? nrow : Npad - 1;
      uint4 ub0 = c4[(size_t)nc * 8 + quad];
      uint4 ub1 = c4[(size_t)nc * 8 + 4 + quad];
      half8 b0, b1;
      __builtin_memcpy(&b0, &ub0, 16); __builtin_memcpy(&b1, &ub1, 16);
      int nl = nrow < N ? nrow : N - 1;
      int lv = A.labels[(size_t)nl << shift];
      floatx4 d0 = __builtin_amdgcn_mfma_f32_16x16x32_f16(a00, b0, z, 0, 0, 0);
      d0 = __builtin_amdgcn_mfma_f32_16x16x32_f16(a01, b1, d0, 0, 0, 0);
      floatx4 d1 = __builtin_amdgcn_mfma_f32_16x16x32_f16(a10, b0, z, 0, 0, 0);
      d1 = __builtin_amdgcn_mfma_f32_16x16x32_f16(a11, b1, d1, 0, 0, 0);
      if (nrow < N) {
#pragma unroll
        for (int r = 0; r < 4; ++r) {
          int rl0 = quad*4 + r, rl1 = 16 + quad*4 + r;
          float v0 = fmaf(d0[r], -0.5f, 50.0f);
          if (v0 < TL0[r]) {
            atomicAdd(&sm.p3.lab[rl0 * NCLS + lv], 1u);            // LDS
          } else if (v0 <= TH0[r]) {
            unsigned pos = atomicAdd(&sm.p3.lcnt[rl0], 1u);        // LDS, local
            if (pos < CAPB)
              A.cand[((size_t)cx * B + (m0 + rl0)) * CAPB + pos] = (unsigned)nrow;
          }
          float v1 = fmaf(d1[r], -0.5f, 50.0f);
          if (v1 < TL1[r]) {
            atomicAdd(&sm.p3.lab[rl1 * NCLS + lv], 1u);
          } else if (v1 <= TH1[r]) {
            unsigned pos = atomicAdd(&sm.p3.lcnt[rl1], 1u);
            if (pos < CAPB)
              A.cand[((size_t)cx * B + (m0 + rl1)) * CAPB + pos] = (unsigned)nrow;
          }
        }
      }
    }
    __syncthreads();
    if (tid < MROWS) {
      unsigned c = sm.p3.lcnt[tid];
      A.ccnt[(size_t)cx * B + (m0 + tid)] = c < CAPB ? c : CAPB;   // plain store
    }
    // below-class merge: fire-and-forget atomics (no return -> no wave stall)
    for (int i = tid; i < MROWS * NCLS; i += 256) {
      unsigned c = sm.p3.lab[i];
      if (c) atomicAdd(&A.belowCnt[(m0 + i / NCLS) * NCLS + i % NCLS], c);
    }
  }
  grid.sync();

  // =============== P4: gather segments, exact f64 resolve, emit probs ===============
  if (blk < B) {
    int b = blk;
    if (tid == 0) sm.p4.btot = 0u;
    if (tid < NCHX) sm.p4.soff[tid + 1] = (int)A.ccnt[(size_t)tid * B + b];
    __syncthreads();
    if (tid == 0) {
      sm.p4.soff[0] = 0;
      for (int s = 0; s < NCHX; ++s) {
        int nx = sm.p4.soff[s] + sm.p4.soff[s + 1];
        sm.p4.soff[s + 1] = nx < CAPC ? nx : CAPC;
      }
    }
    for (int c = tid; c < NCLS; c += 256) {
      unsigned v = A.belowCnt[b * NCLS + c];
      if (v) atomicAdd(&sm.p4.btot, v);
    }
    __syncthreads();
    int cnt = sm.p4.soff[NCHX];
    for (int s = tid; s < NCHX; s += 256) {      // gather: ~4 entries/segment
      int c0 = sm.p4.soff[s], c1 = sm.p4.soff[s + 1];
      const unsigned* seg = A.cand + ((size_t)s * B + b) * CAPB;
      for (int j = 0; j < c1 - c0; ++j) sm.p4.kidx[c0 + j] = (int)seg[j];
    }
    __syncthreads();
    int K = A.Kp[0];
    int need = K - (int)sm.p4.btot;
    int M = 1; while (M < cnt) M <<= 1;
    const double* od = A.out64 + (size_t)b * 64;
    for (int i = tid; i < M; i += 256) {
      if (i < cnt) {
        sm.p4.key[i] = fma(dot1(A.codes, sm.p4.kidx[i], od), -0.5, 50.0);
      } else { sm.p4.key[i] = __builtin_inf(); sm.p4.kidx[i] = 0x7FFFFFFF; }
    }
    __syncthreads();
    for (int size = 2; size <= M; size <<= 1) {
      for (int stride = size >> 1; stride > 0; stride >>= 1) {
        for (int i = tid; i < M; i += 256) {
          int j = i ^ stride;
          if (j > i) {
            double ki = sm.p4.key[i], kj = sm.p4.key[j];
            int ii = sm.p4.kidx[i], ij = sm.p4.kidx[j];
            bool up = ((i & size) == 0);
            bool sw = up ? (kj < ki || (kj == ki && ij < ii))
                         : (kj > ki || (kj == ki && ij > ii));
            if (sw) { sm.p4.key[i] = kj; sm.p4.key[j] = ki;
                      sm.p4.kidx[i] = ij; sm.p4.kidx[j] = ii; }
          }
        }
        __syncthreads();
      }
    }
    for (int i = tid; i < NCLS; i += 256) sm.p4.lab[i] = 0u;
    __syncthreads();
    int shift = A.scal->shift;
    int take = need < cnt ? need : cnt;
    if (take < 0) take = 0;
    for (int i = tid; i < take; i += 256)
      atomicAdd(&sm.p4.lab[A.labels[(size_t)sm.p4.kidx[i] << shift]], 1u);
    __syncthreads();
    double Kd = (double)K;
    for (int c = tid; c < NCLS; c += 256)
      A.outp[b * NCLS + c] = (float)((double)(A.belowCnt[b * NCLS + c] + sm.p4.lab[c]) / Kd);
  }
}

extern "C" void kernel_launch(void* const* d_in, const int* in_sizes, int n_in,
                              void* d_out, int out_size, void* d_ws, size_t ws_size,
                              hipStream_t stream) {
  const float* x     = (const float*)d_in[0];
  const float* W     = (const float*)d_in[1];
  const float* codes = (const float*)d_in[2];
  const int* labels  = (const int*)d_in[3];
  const int* Kp      = (const int*)d_in[4];

  const int B = out_size / NCLS;             // 256
  const int N = in_sizes[3];                 // 100000
  const int D = in_sizes[0] / B;             // 2048
  const int Npad = (N + 255) & ~255;         // 100096
  const int cpb = (((N + NCHX - 1) / NCHX) + 63) & ~63;  // 1600 codes per chunk

  // ws layout; all zeroing now in-kernel (P0a) — no memset dispatch.
  char* p = (char*)d_ws;
  double* out64      = (double*)p;   p += (size_t)B * 64 * sizeof(double);       // 128 KB
  float2* rowTH      = (float2*)p;   p += (size_t)B * sizeof(float2);            // 2 KB
  unsigned short* out16 = (unsigned short*)p; p += (size_t)B * 64 * 2;           // 32 KB
  double* B1sq       = (double*)p;   p += (size_t)B * sizeof(double);            // 2 KB
  Scal* scal         = (Scal*)p;     p += 64;
  unsigned* belowCnt = (unsigned*)p; p += (size_t)B * NCLS * sizeof(unsigned);   // 100 KB
  unsigned* ccnt     = (unsigned*)p; p += (size_t)NCHX * B * sizeof(unsigned);   // 64 KB
  unsigned* cand     = (unsigned*)p; p += (size_t)NCHX * B * CAPB * sizeof(unsigned); // 4 MB
  unsigned short* histg = (unsigned short*)p; p += (size_t)NCHX * B * NBK * sizeof(unsigned short); // 8 MB
  unsigned short* codes16 = (unsigned short*)p;                                  // 12.8 MB

  KArgs ka;
  ka.x = x; ka.W = W; ka.codes = codes; ka.labels = labels; ka.Kp = Kp;
  ka.out64 = out64; ka.rowTH = rowTH; ka.out16 = out16; ka.B1sq = B1sq;
  ka.scal = scal; ka.belowCnt = belowCnt; ka.ccnt = ccnt; ka.cand = cand;
  ka.histg = histg; ka.codes16 = codes16; ka.outp = (float*)d_out;
  ka.N = N; ka.Npad = Npad; ka.cpb = cpb; ka.B = B; ka.D = D;

  void* args[] = { &ka };
  int nblk = NCHX * (B / MROWS);             // 512 blocks, 2/CU co-resident
  hipLaunchCooperativeKernel((void*)k_fused, dim3(nblk), dim3(256), args, 0, stream);
}